// Round 12
// baseline (142.964 us; speedup 1.0000x reference)
//
#include <hip/hip_runtime.h>
#include <hip/hip_bf16.h>
#include <cstdint>

// TT-linear: y[4096,4096] = x[4096,1024] @ W[1024,4096] + bias
// Kernel 1 (prep): fused x->bf16 convert + W^T reconstruction from TT cores (unchanged).
// Kernel 2 (tt_gemm): Round-12 = extend the ONLY axis that has paid (per-CU
//   concurrency): 3 blocks/CU. Block 128x128, BK=32, 3-slot ring = 48 KB LDS
//   (160/48 -> 3 resident), 4 waves of 64x64 (R10-proven read:MFMA=1.23 shape),
//   256 threads, grid 1024. Session A/Bs carried: swizzle phys=logical^((r>>1)&3)
//   both sides (0 conflicts: R5/R7/R10), coarse free-run tile body (R7: beats
//   8-phase lockstep), stage-2-ahead ring with counted WAITVM(4) (never drains
//   mid-loop), 1 barrier/tile, bijective XCD patch map, ni-inner epilogue,
//   16x16x32 MFMA only (32x32 read shape conflicts under HW batch pairing).
//   Mechanism: third independent K-loop per CU fills latency bubbles and
//   overlaps neighbor epilogues with compute (R5->R10 gains came from 8->16
//   waves/CU; this goes to 12 waves with a smaller, still-balanced block).

typedef __bf16 bf16x8 __attribute__((ext_vector_type(8)));
typedef float f32x4 __attribute__((ext_vector_type(4)));

__device__ __forceinline__ void g2lds16(const void* g, void* l) {
    __builtin_amdgcn_global_load_lds(
        (const __attribute__((address_space(1))) void*)g,
        (__attribute__((address_space(3))) void*)l,
        16, 0, 0);
}

// --------------------------------------------------------------------- prep
__global__ __launch_bounds__(256) void prep(
    const float* __restrict__ x, __bf16* __restrict__ xb,
    const float* __restrict__ c0, const float* __restrict__ c1,
    const float* __restrict__ c2, const float* __restrict__ c3,
    __bf16* __restrict__ wt) {
    const int b = blockIdx.x;
    const int t = threadIdx.x;
    if (b < 2048) {
        const int i = (b * 256 + t) * 8;
        float4 a0 = *(const float4*)(x + i);
        float4 a1 = *(const float4*)(x + i + 4);
        bf16x8 o;
        o[0] = (__bf16)a0.x; o[1] = (__bf16)a0.y; o[2] = (__bf16)a0.z; o[3] = (__bf16)a0.w;
        o[4] = (__bf16)a1.x; o[5] = (__bf16)a1.y; o[6] = (__bf16)a1.z; o[7] = (__bf16)a1.w;
        *(bf16x8*)(xb + i) = o;
        return;
    }
    __shared__ float t12[4][16];     // [wave][r2]
    __shared__ float t123[4][512];   // [wave][m3*8+n3][r3]
    __shared__ float c3s[512];       // [(r3*4+m4)*8+n4]
    #pragma unroll
    for (int i = t; i < 512; i += 256) c3s[i] = c3[i];
    const int s = t >> 6;
    const int lane = t & 63;
    const int g = (b - 2048) * 4 + s;
    const int m1 = g >> 9, n1 = (g >> 6) & 7, m2 = (g >> 3) & 7, n2 = g & 7;
    __syncthreads();
    if (lane < 16) {
        const int r2 = lane;
        float sum = 0.f;
        #pragma unroll
        for (int r1 = 0; r1 < 16; ++r1)
            sum += c0[(m1 * 8 + n1) * 16 + r1] * c1[((r1 * 8 + m2) * 8 + n2) * 16 + r2];
        t12[s][r2] = sum;
    }
    __syncthreads();
    #pragma unroll
    for (int idx = lane; idx < 512; idx += 64) {
        const int m3 = idx >> 7, n3 = (idx >> 4) & 7, r3 = idx & 15;
        float sum = 0.f;
        #pragma unroll
        for (int r2 = 0; r2 < 16; ++r2)
            sum += t12[s][r2] * c2[((r2 * 4 + m3) * 8 + n3) * 16 + r3];
        t123[s][(m3 * 8 + n3) * 16 + r3] = sum;
    }
    __syncthreads();
    const int n3 = lane >> 3, n4 = lane & 7;
    const int n = ((n1 * 8 + n2) * 8 + n3) * 8 + n4;
    const int kbase = (m1 * 8 + m2) * 16;
    float v[16];
    #pragma unroll
    for (int e = 0; e < 16; ++e) v[e] = 0.f;
    #pragma unroll
    for (int m3 = 0; m3 < 4; ++m3) {
        #pragma unroll
        for (int r3 = 0; r3 < 16; ++r3) {
            const float tv = t123[s][(m3 * 8 + n3) * 16 + r3];
            #pragma unroll
            for (int m4 = 0; m4 < 4; ++m4)
                v[m3 * 4 + m4] += tv * c3s[(r3 * 4 + m4) * 8 + n4];
        }
    }
    bf16x8 lo, hi;
    #pragma unroll
    for (int e = 0; e < 8; ++e) { lo[e] = (__bf16)v[e]; hi[e] = (__bf16)v[8 + e]; }
    *(bf16x8*)(wt + (size_t)n * 1024 + kbase)     = lo;
    *(bf16x8*)(wt + (size_t)n * 1024 + kbase + 8) = hi;
}

// -------------------------------------------------------------- GEMM + bias
// C[4096,4096] f32 = A[4096,1024] bf16 @ Bt[4096,1024]^T bf16 + bias
// Geometry: BM=BN=128, BK=32 (32 K-tiles), 4 waves 2Mx2N (wave 64x64),
// 256 threads, grid 1024 (32 bm x 32 bn), 3 blocks/CU (LDS 48 KB).
// LDS ring: sA[3][128x32] + sB[3][128x32] = 48 KB; tile kt in slot kt%3,
// staged during kt-2 (4 g2lds16/thread). WAITVM(4) at end of kt: 8 outstanding
// (kt+1:4, kt+2:4), waits oldest 4 => kt+1 fully in LDS; never drains.
// Slot safety: ST(kt+2) targets slot(kt-1); its readers retired before the
// end-of-(kt-1) barrier (ds_read data consumed by MFMA before BAR).
// Swizzle: 64-B rows, 4 x 16B chunks, phys = logical ^ ((row>>1)&3) on both
// staging-source and read sides (R5/R7/R10-verified: 0 conflicts).

#define SCHED() __builtin_amdgcn_sched_barrier(0)
#define BAR()  do { SCHED(); __builtin_amdgcn_s_barrier(); SCHED(); } while (0)
#define WAITVM(n) do { SCHED(); asm volatile("s_waitcnt vmcnt(" #n ")"); SCHED(); } while (0)

__global__ __launch_bounds__(256, 3) void tt_gemm(
    const __bf16* __restrict__ A, const __bf16* __restrict__ B,
    const float* __restrict__ bias, float* __restrict__ C) {
    constexpr int K = 1024, N = 4096;
    constexpr int NKT = 32;                  // K-tiles of 32
    __shared__ __bf16 sA[3][128 * 32];       // 3 x 8 KB
    __shared__ __bf16 sB[3][128 * 32];       // 3 x 8 KB
    const int t = threadIdx.x;
    const int lane = t & 63;
    const int wave = t >> 6;                 // 0..3
    const int wm = (wave >> 1) * 64;         // 0 / 64  (M range of wave)
    const int wn = (wave & 1) * 64;          // 0 / 64  (N range of wave)
    const int l15 = lane & 15, lh = lane >> 4;
    const int cOff = ((lh ^ ((l15 >> 1) & 3)) << 4);  // swizzled 16B chunk in 64-B row

    // XCD-aware mapping: each XCD owns a 16bm x 8bn patch (bijective, 1024 blocks)
    const int xcd = blockIdx.x & 7;
    const int lid = blockIdx.x >> 3;         // 0..127
    const int bm = ((xcd >> 2) * 16 + (lid & 15)) * 128;  // 32 bm values
    const int bn = ((xcd & 3) * 8 + (lid >> 4)) * 128;    // 32 bn values

    // staging: each tile = 512 x 16B chunks; thread owns chunks t and t+256
    const __bf16* ap[2];
    const __bf16* bp[2];
    #pragma unroll
    for (int j = 0; j < 2; ++j) {
        const int c = t + j * 256;
        const int r = c >> 2;                            // row 0..127
        const int lc = (c & 3) ^ ((r >> 1) & 3);         // logical chunk (global)
        ap[j] = A + (size_t)(bm + r) * K + lc * 8;
        bp[j] = B + (size_t)(bn + r) * K + lc * 8;
    }

#define ST(kt, sl) do { \
    _Pragma("unroll") \
    for (int j = 0; j < 2; ++j) { \
        g2lds16(ap[j] + (size_t)(kt) * 32, (char*)&sA[sl][0] + (t + j * 256) * 16); \
        g2lds16(bp[j] + (size_t)(kt) * 32, (char*)&sB[sl][0] + (t + j * 256) * 16); \
    } \
} while (0)
#define LDA(dst, mi) dst = *(const bf16x8*)((const char*)&sA[s0][0] + (wm + (mi) * 16 + l15) * 64 + cOff)
#define LDB(dst, ni) dst = *(const bf16x8*)((const char*)&sB[s0][0] + (wn + (ni) * 16 + l15) * 64 + cOff)

    f32x4 acc[4][4] = {};

    // prologue: stage tiles 0 (slot0) and 1 (slot1) = 8 loads; oldest 4 = tile 0
    ST(0, 0);
    ST(1, 1);
    WAITVM(4);
    BAR();

    #pragma unroll 1
    for (int kt = 0; kt < NKT; ++kt) {
        const int s0 = kt % 3;
        const int s2 = (kt + 2) % 3;
        bf16x8 af[4], bf[4];
        // 8 frag reads; stage kt+2; 16 MFMA; counted wait; barrier
        #pragma unroll
        for (int mi = 0; mi < 4; ++mi) LDA(af[mi], mi);
        #pragma unroll
        for (int ni = 0; ni < 4; ++ni) LDB(bf[ni], ni);
        if (kt < NKT - 2) ST(kt + 2, s2);
        __builtin_amdgcn_s_setprio(1);
        #pragma unroll
        for (int mi = 0; mi < 4; ++mi)
            #pragma unroll
            for (int ni = 0; ni < 4; ++ni)
                acc[mi][ni] = __builtin_amdgcn_mfma_f32_16x16x32_bf16(
                    af[mi], bf[ni], acc[mi][ni], 0, 0, 0);
        __builtin_amdgcn_s_setprio(0);
        if (kt < NKT - 2)       { WAITVM(4); }   // gates kt+1; never drains
        else if (kt == NKT - 2) { WAITVM(0); }   // drain for final tile
        BAR();
    }

    // epilogue: C/D layout col=lane&15, row=(lane>>4)*4+reg (m89-verified);
    // ni-inner store order -> 256B contiguous per wave-row
    float bv[4];
    #pragma unroll
    for (int ni = 0; ni < 4; ++ni) bv[ni] = bias[bn + wn + ni * 16 + l15];
    #pragma unroll
    for (int mi = 0; mi < 4; ++mi) {
        #pragma unroll
        for (int r = 0; r < 4; ++r) {
            const int row = bm + wm + mi * 16 + lh * 4 + r;
            float* crow = C + (size_t)row * N + bn + wn + l15;
            #pragma unroll
            for (int ni = 0; ni < 4; ++ni)
                crow[ni * 16] = acc[mi][ni][r] + bv[ni];
        }
    }
#undef ST
#undef LDA
#undef LDB
}

extern "C" void kernel_launch(void* const* d_in, const int* in_sizes, int n_in,
                              void* d_out, int out_size, void* d_ws, size_t ws_size,
                              hipStream_t stream) {
    const float* x    = (const float*)d_in[0];
    const float* c0   = (const float*)d_in[1];
    const float* c1   = (const float*)d_in[2];
    const float* c2   = (const float*)d_in[3];
    const float* c3   = (const float*)d_in[4];
    const float* bias = (const float*)d_in[5];
    float* out = (float*)d_out;

    __bf16* xb = (__bf16*)d_ws;                    // 4096*1024 bf16 = 8.39 MB
    __bf16* wt = xb + (size_t)4096 * 1024;         // 4096*1024 bf16 = 8.39 MB

    prep<<<3072, 256, 0, stream>>>(x, xb, c0, c1, c2, c3, wt);
    tt_gemm<<<1024, 256, 0, stream>>>(xb, wt, bias, out);
}

// Round 13
// 136.269 us; speedup vs baseline: 1.0491x; 1.0491x over previous
//
#include <hip/hip_runtime.h>
#include <hip/hip_bf16.h>
#include <cstdint>

// TT-linear: y[4096,4096] = x[4096,1024] @ W[1024,4096] + bias
// Kernel 1 (prep): fused x->bf16 convert + W^T reconstruction from TT cores.
// Kernel 2 (tt_gemm): FINAL = Round-10 configuration, the session's measured
//   optimum of 13 structural variants (every instance < 45.6 us; R12's 128^2
//   3-block variant regressed to 53 us via FETCH 24.6->41 MB reuse loss).
//   Block 256x128, 8 waves of 64x64, BK=32, 3-slot LDS ring 72 KB -> 2
//   blocks/CU. Session-verified mechanisms: 16x16x32 MFMA (32x32 read shape
//   conflicts under HW batch pairing regardless of XOR: R8/R9 = identical
//   3.1M cyc), swizzle phys=logical^((row>>1)&3) on both staging-source and
//   read sides (0 conflicts: R5/R7/R10/R11), coarse free-run tile body
//   (beats 8-phase lockstep: R7), stage-2-ahead ring with counted WAITVM(3)
//   (never drains mid-loop), 1 barrier/tile, bijective XCD patch map,
//   ni-inner epilogue (WRITE_SIZE ~ideal 65.5 MB).

typedef __bf16 bf16x8 __attribute__((ext_vector_type(8)));
typedef float f32x4 __attribute__((ext_vector_type(4)));

__device__ __forceinline__ void g2lds16(const void* g, void* l) {
    __builtin_amdgcn_global_load_lds(
        (const __attribute__((address_space(1))) void*)g,
        (__attribute__((address_space(3))) void*)l,
        16, 0, 0);
}

// --------------------------------------------------------------------- prep
__global__ __launch_bounds__(256) void prep(
    const float* __restrict__ x, __bf16* __restrict__ xb,
    const float* __restrict__ c0, const float* __restrict__ c1,
    const float* __restrict__ c2, const float* __restrict__ c3,
    __bf16* __restrict__ wt) {
    const int b = blockIdx.x;
    const int t = threadIdx.x;
    if (b < 2048) {
        const int i = (b * 256 + t) * 8;
        float4 a0 = *(const float4*)(x + i);
        float4 a1 = *(const float4*)(x + i + 4);
        bf16x8 o;
        o[0] = (__bf16)a0.x; o[1] = (__bf16)a0.y; o[2] = (__bf16)a0.z; o[3] = (__bf16)a0.w;
        o[4] = (__bf16)a1.x; o[5] = (__bf16)a1.y; o[6] = (__bf16)a1.z; o[7] = (__bf16)a1.w;
        *(bf16x8*)(xb + i) = o;
        return;
    }
    __shared__ float t12[4][16];     // [wave][r2]
    __shared__ float t123[4][512];   // [wave][m3*8+n3][r3]
    __shared__ float c3s[512];       // [(r3*4+m4)*8+n4]
    #pragma unroll
    for (int i = t; i < 512; i += 256) c3s[i] = c3[i];
    const int s = t >> 6;
    const int lane = t & 63;
    const int g = (b - 2048) * 4 + s;
    const int m1 = g >> 9, n1 = (g >> 6) & 7, m2 = (g >> 3) & 7, n2 = g & 7;
    __syncthreads();
    if (lane < 16) {
        const int r2 = lane;
        float sum = 0.f;
        #pragma unroll
        for (int r1 = 0; r1 < 16; ++r1)
            sum += c0[(m1 * 8 + n1) * 16 + r1] * c1[((r1 * 8 + m2) * 8 + n2) * 16 + r2];
        t12[s][r2] = sum;
    }
    __syncthreads();
    #pragma unroll
    for (int idx = lane; idx < 512; idx += 64) {
        const int m3 = idx >> 7, n3 = (idx >> 4) & 7, r3 = idx & 15;
        float sum = 0.f;
        #pragma unroll
        for (int r2 = 0; r2 < 16; ++r2)
            sum += t12[s][r2] * c2[((r2 * 4 + m3) * 8 + n3) * 16 + r3];
        t123[s][(m3 * 8 + n3) * 16 + r3] = sum;
    }
    __syncthreads();
    const int n3 = lane >> 3, n4 = lane & 7;
    const int n = ((n1 * 8 + n2) * 8 + n3) * 8 + n4;
    const int kbase = (m1 * 8 + m2) * 16;
    float v[16];
    #pragma unroll
    for (int e = 0; e < 16; ++e) v[e] = 0.f;
    #pragma unroll
    for (int m3 = 0; m3 < 4; ++m3) {
        #pragma unroll
        for (int r3 = 0; r3 < 16; ++r3) {
            const float tv = t123[s][(m3 * 8 + n3) * 16 + r3];
            #pragma unroll
            for (int m4 = 0; m4 < 4; ++m4)
                v[m3 * 4 + m4] += tv * c3s[(r3 * 4 + m4) * 8 + n4];
        }
    }
    bf16x8 lo, hi;
    #pragma unroll
    for (int e = 0; e < 8; ++e) { lo[e] = (__bf16)v[e]; hi[e] = (__bf16)v[8 + e]; }
    *(bf16x8*)(wt + (size_t)n * 1024 + kbase)     = lo;
    *(bf16x8*)(wt + (size_t)n * 1024 + kbase + 8) = hi;
}

// -------------------------------------------------------------- GEMM + bias
// C[4096,4096] f32 = A[4096,1024] bf16 @ Bt[4096,1024]^T bf16 + bias
// Geometry: BM=256, BN=128, BK=32 (32 K-tiles), 8 waves 4Mx2N (wave 64x64),
// 512 threads, grid 512 (16 bm x 32 bn), 2 blocks/CU (LDS 72 KB, <=128 regs).
// LDS ring: sA[3][256x32] + sB[3][128x32] = 72 KB; tile kt in slot kt%3,
// staged during kt-2. WAITVM(3) at end of kt: 6 outstanding (kt+1:3, kt+2:3),
// waits oldest 3 => kt+1 fully in LDS. Slot safety: ST(kt+2) targets slot
// (kt+2)%3 = slot(kt-1), whose readers finished before the end-of-(kt-1)
// barrier. Swizzle: 64-B rows, 4 x 16B chunks, phys = logical ^ ((row>>1)&3)
// on both staging-source and read sides (verified 0 conflicts).

#define SCHED() __builtin_amdgcn_sched_barrier(0)
#define BAR()  do { SCHED(); __builtin_amdgcn_s_barrier(); SCHED(); } while (0)
#define WAITVM(n) do { SCHED(); asm volatile("s_waitcnt vmcnt(" #n ")"); SCHED(); } while (0)

__global__ __launch_bounds__(512, 4) void tt_gemm(
    const __bf16* __restrict__ A, const __bf16* __restrict__ B,
    const float* __restrict__ bias, float* __restrict__ C) {
    constexpr int K = 1024, N = 4096;
    constexpr int NKT = 32;                  // K-tiles of 32
    __shared__ __bf16 sA[3][256 * 32];       // 3 x 16 KB
    __shared__ __bf16 sB[3][128 * 32];       // 3 x 8 KB
    const int t = threadIdx.x;
    const int lane = t & 63;
    const int wave = t >> 6;                 // 0..7
    const int wm = (wave >> 1) * 64;         // 0..192  (M range of wave)
    const int wn = (wave & 1) * 64;          // 0 / 64  (N range of wave)
    const int l15 = lane & 15, lh = lane >> 4;
    const int cOff = ((lh ^ ((l15 >> 1) & 3)) << 4);  // swizzled 16B chunk in 64-B row

    // XCD-aware mapping: each XCD owns an 8bm x 8bn patch (bijective, 512 blocks)
    const int xcd = blockIdx.x & 7;
    const int lid = blockIdx.x >> 3;         // 0..63
    const int bm = ((xcd >> 2) * 8 + (lid & 7)) * 256;   // 16 bm values
    const int bn = ((xcd & 3) * 8 + (lid >> 3)) * 128;   // 32 bn values

    // staging: A tile = 1024 chunks of 16B (thread owns t, t+512);
    //          B tile = 512 chunks (thread owns t)
    const int c0i = t, c1i = t + 512;
    const int rA0 = c0i >> 2, rA1 = c1i >> 2;            // A row 0..255
    const int lcA0 = (c0i & 3) ^ ((rA0 >> 1) & 3);       // logical chunk (global)
    const int lcA1 = (c1i & 3) ^ ((rA1 >> 1) & 3);
    const int rB = t >> 2;                               // B row 0..127
    const int lcB = (t & 3) ^ ((rB >> 1) & 3);
    const __bf16* a0p = A + (size_t)(bm + rA0) * K + lcA0 * 8;
    const __bf16* a1p = A + (size_t)(bm + rA1) * K + lcA1 * 8;
    const __bf16* bp  = B + (size_t)(bn + rB)  * K + lcB * 8;

#define ST(kt, sl) do { \
    g2lds16(a0p + (size_t)(kt) * 32, (char*)&sA[sl][0] + c0i * 16); \
    g2lds16(a1p + (size_t)(kt) * 32, (char*)&sA[sl][0] + c1i * 16); \
    g2lds16(bp  + (size_t)(kt) * 32, (char*)&sB[sl][0] + t * 16); } while (0)
#define LDA(dst, mi) dst = *(const bf16x8*)((const char*)&sA[s0][0] + (wm + (mi) * 16 + l15) * 64 + cOff)
#define LDB(dst, ni) dst = *(const bf16x8*)((const char*)&sB[s0][0] + (wn + (ni) * 16 + l15) * 64 + cOff)

    f32x4 acc[4][4] = {};

    // prologue: stage tiles 0 (slot0) and 1 (slot1) = 6 loads; oldest 3 = tile 0
    ST(0, 0);
    ST(1, 1);
    WAITVM(3);
    BAR();

    #pragma unroll 1
    for (int kt = 0; kt < NKT; ++kt) {
        const int s0 = kt % 3;
        const int s2 = (kt + 2) % 3;
        bf16x8 af[4], bf[4];
        // all 8 frag reads hoisted; stage kt+2; 16 MFMA; counted wait; barrier
        #pragma unroll
        for (int mi = 0; mi < 4; ++mi) LDA(af[mi], mi);
        #pragma unroll
        for (int ni = 0; ni < 4; ++ni) LDB(bf[ni], ni);
        if (kt < NKT - 2) ST(kt + 2, s2);
        __builtin_amdgcn_s_setprio(1);
        #pragma unroll
        for (int mi = 0; mi < 4; ++mi)
            #pragma unroll
            for (int ni = 0; ni < 4; ++ni)
                acc[mi][ni] = __builtin_amdgcn_mfma_f32_16x16x32_bf16(
                    af[mi], bf[ni], acc[mi][ni], 0, 0, 0);
        __builtin_amdgcn_s_setprio(0);
        if (kt < NKT - 2)       { WAITVM(3); }   // gates kt+1; never drains
        else if (kt == NKT - 2) { WAITVM(0); }   // drain for final tile
        BAR();
    }

    // epilogue: C/D layout col=lane&15, row=(lane>>4)*4+reg (m89-verified);
    // ni-inner store order -> 256B contiguous per wave-row
    float bv[4];
    #pragma unroll
    for (int ni = 0; ni < 4; ++ni) bv[ni] = bias[bn + wn + ni * 16 + l15];
    #pragma unroll
    for (int mi = 0; mi < 4; ++mi) {
        #pragma unroll
        for (int r = 0; r < 4; ++r) {
            const int row = bm + wm + mi * 16 + lh * 4 + r;
            float* crow = C + (size_t)row * N + bn + wn + l15;
            #pragma unroll
            for (int ni = 0; ni < 4; ++ni)
                crow[ni * 16] = acc[mi][ni][r] + bv[ni];
        }
    }
#undef ST
#undef LDA
#undef LDB
}

extern "C" void kernel_launch(void* const* d_in, const int* in_sizes, int n_in,
                              void* d_out, int out_size, void* d_ws, size_t ws_size,
                              hipStream_t stream) {
    const float* x    = (const float*)d_in[0];
    const float* c0   = (const float*)d_in[1];
    const float* c1   = (const float*)d_in[2];
    const float* c2   = (const float*)d_in[3];
    const float* c3   = (const float*)d_in[4];
    const float* bias = (const float*)d_in[5];
    float* out = (float*)d_out;

    __bf16* xb = (__bf16*)d_ws;                    // 4096*1024 bf16 = 8.39 MB
    __bf16* wt = xb + (size_t)4096 * 1024;         // 4096*1024 bf16 = 8.39 MB

    prep<<<3072, 256, 0, stream>>>(x, xb, c0, c1, c2, c3, wt);
    tt_gemm<<<512, 512, 0, stream>>>(xb, wt, bias, out);
}